// Round 9
// baseline (269.436 us; speedup 1.0000x reference)
//
#include <hip/hip_runtime.h>
#include <stdint.h>

// out[M,N] = x[M,K] @ dequant(W_q_packed)[K,N] + bias[N]
// M=N=K=4096, 4-bit nibbles packed 8/int32 along K, GROUP=128.
// R14: TLP pivot. Free-run schedules (R10/11/13) kill the container 3/3;
// barrier-bounded ones run 5/5 -> free-run abandoned. R12 datum: 125.9us,
// MfmaUtil 48%, occupancy 21% (1 block/CU, 2 waves/SIMD) - stalls have
// nothing to overlap with. Fix: 2 blocks/CU. Tile 256x128, grid 512, 8
// waves (4Mx2N, per-wave 64x64, acc=64), BK=32, 2-ring LDS 48KB/block,
// __launch_bounds__(512,4) -> 4 waves/SIMD. Proven-safe drain-0 loop
// (stage t+1 -> read 8 frags -> 16 MFMA -> vmcnt(0) -> barrier); the
// per-tile drain now overlaps the co-resident block's compute.
// LDS XOR-cell layout (cell=row*4+(kc^((row>>1)&3)), pre-swizzled global
// source, swizzled read) - R12-verified, 0 bank conflicts.
// XCD swizzle: each XCD owns 4 B-panels of 128 (4MB = its L2).
// Prep split (cvt/dequant) kept to localize the ~130us non-gemm time.

#define M_DIM 4096
#define N_DIM 4096
#define K_DIM 4096

typedef __attribute__((ext_vector_type(8))) short short8;
typedef __attribute__((ext_vector_type(4))) float f32x4;

__device__ __forceinline__ unsigned short f2bf(float f) {
  uint32_t u = __builtin_bit_cast(uint32_t, f);
  u += 0x7fffu + ((u >> 16) & 1u);   // round-to-nearest-even
  return (unsigned short)(u >> 16);
}

// ---------- kernel 1a: x fp32 -> bf16 (ushort8 stores) ----------
__global__ __launch_bounds__(256) void cvt_kernel(const float* __restrict__ x,
                                                  unsigned short* __restrict__ xb) {
  const int tid = threadIdx.x;
  const int total = (M_DIM * K_DIM) / 8;   // 2M ushort8
  const float4* x4 = (const float4*)x;
  uint4* o8 = (uint4*)xb;
#pragma unroll
  for (int p = 0; p < 4; ++p) {
    int i = (p * 2048 + blockIdx.x) * 256 + tid;
    if (i < total) {
      float4 a = x4[2 * i], b = x4[2 * i + 1];
      uint4 o;
      o.x = (uint32_t)f2bf(a.x) | ((uint32_t)f2bf(a.y) << 16);
      o.y = (uint32_t)f2bf(a.z) | ((uint32_t)f2bf(a.w) << 16);
      o.z = (uint32_t)f2bf(b.x) | ((uint32_t)f2bf(b.y) << 16);
      o.w = (uint32_t)f2bf(b.z) | ((uint32_t)f2bf(b.w) << 16);
      o8[i] = o;
    }
  }
}

// ---------- kernel 1b: dequant + transpose -> W^T (N x K) bf16 ----------
__global__ __launch_bounds__(256) void dequant_kernel(const int* __restrict__ Wq,
                                                      const float* __restrict__ scales,
                                                      const float* __restrict__ zeros,
                                                      unsigned short* __restrict__ wt) {
  __shared__ uint4 Ts[32 * 64];  // 32 KB
  const int tid = threadIdx.x;
  const int blk = blockIdx.x;
  const int n0 = (blk & 127) * 32;        // N/32 = 128 tiles
  const int gk0 = (blk >> 7) * 64;        // (K/8)/64 = 8 tiles

#pragma unroll
  for (int p = 0; p < 8; ++p) {
    int e = p * 256 + tid;
    int n_l = e & 31;
    int gk_l = e >> 5;
    int gk = gk0 + gk_l;
    int n = n0 + n_l;
    int g = gk >> 4;                // group = (gk*8)/128
    uint32_t q = (uint32_t)Wq[gk * N_DIM + n];
    float s = scales[g * N_DIM + n];
    float z = zeros[g * N_DIM + n];
    unsigned short b[8];
#pragma unroll
    for (int j = 0; j < 8; ++j) {
      float f = ((float)((q >> (4 * j)) & 15u) - z) * s;
      b[j] = f2bf(f);
    }
    uint4 cell;
    cell.x = (uint32_t)b[0] | ((uint32_t)b[1] << 16);
    cell.y = (uint32_t)b[2] | ((uint32_t)b[3] << 16);
    cell.z = (uint32_t)b[4] | ((uint32_t)b[5] << 16);
    cell.w = (uint32_t)b[6] | ((uint32_t)b[7] << 16);
    Ts[n_l * 64 + (gk_l ^ (n_l & 7))] = cell;
  }
  __syncthreads();
  uint4* dst = (uint4*)wt;
#pragma unroll
  for (int p = 0; p < 8; ++p) {
    int n_l = p * 4 + (tid >> 6);
    int gk_l = tid & 63;
    uint4 cell = Ts[n_l * 64 + (gk_l ^ (n_l & 7))];
    dst[(size_t)(n0 + n_l) * (K_DIM / 8) + (gk0 + gk_l)] = cell;
  }
}

// ---------- kernel 2: bf16 GEMM, C = A @ Bt^T + bias ----------
// 256x128 tile, 8 waves (wm 0..3, wn 0..1), per-wave 64x64 = acc[4][4] of
// 16x16x32 MFMA (one MFMA consumes full BK=32). 2-ring LDS: A 2x16KB,
// B 2x8KB. Per K-tile per wave: 8 ds_read_b128 + 16 MFMA.

#define ASBUF(T) (As + ((T) & 1) * 1024)
#define BSBUF(T) (Bs + ((T) & 1) * 512)

#define GLDS(DST, SRC)                                                          \
  __builtin_amdgcn_global_load_lds(                                             \
      (const __attribute__((address_space(1))) void*)(SRC),                     \
      (__attribute__((address_space(3))) void*)(DST), 16, 0, 0)

// stage tile T (A: 2 GLDS covering 256 rows; B: 1 GLDS covering 128 rows)
#define STAGE(T)                                                                \
  {                                                                             \
    const unsigned short* as = Asrc + (size_t)(T) * 32;                         \
    const unsigned short* bs = Bsrc + (size_t)(T) * 32;                         \
    GLDS(ASBUF(T) + tid, as);                                                   \
    GLDS(ASBUF(T) + tid + 512, as + (size_t)128 * K_DIM);                       \
    GLDS(BSBUF(T) + tid, bs);                                                   \
  }

#define SB0 __builtin_amdgcn_sched_barrier(0)

__global__ __launch_bounds__(512, 4) void gemm_bt_kernel(
    const unsigned short* __restrict__ A, const unsigned short* __restrict__ Bt,
    const float* __restrict__ bias, float* __restrict__ C) {
  __shared__ short8 As[2 * 1024];  // 32 KB: 2-ring of 256x32 bf16
  __shared__ short8 Bs[2 * 512];   // 16 KB: 2-ring of 128x32 bf16

  const int tid = threadIdx.x;
  const int lane = tid & 63;
  const int w = tid >> 6;      // 0..7
  const int wm = w >> 1;       // 0..3
  const int wn = w & 1;        // 0..1

  // XCD swizzle: 512 blocks; xcd owns nt in [4*xcd, 4*xcd+4) (4MB of B = L2)
  const int b = blockIdx.x;
  const int xcd = b & 7;
  const int loc = b >> 3;              // 0..63
  const int nt = xcd * 4 + (loc & 3);  // 0..31
  const int mt = loc >> 2;             // 0..15
  const int m0 = mt * 256;
  const int n0 = nt * 128;

  // staging: A cells tid (rows 0..127) / tid+512 (rows 128..255); B cells tid
  const int srow = tid >> 2;                        // 0..127
  const int skc = (tid & 3) ^ ((srow >> 1) & 3);    // swizzle inv under +128
  const unsigned short* Asrc = A + (size_t)(m0 + srow) * K_DIM + skc * 8;
  const unsigned short* Bsrc = Bt + (size_t)(n0 + srow) * K_DIM + skc * 8;

  // fragment read addressing: idx = row*4 + (fc ^ ((row>>1)&3))
  const int fr = lane & 15;            // row-low (A) / col-low (B)
  const int fc = lane >> 4;            // k-quarter 0..3
  const int kxs = fc ^ ((fr >> 1) & 3);
  const int a_b = (wm * 64 + fr) * 4 + kxs;
  const int b_b = (wn * 64 + fr) * 4 + kxs;

  f32x4 acc[4][4] = {};

  // prologue: stage tile 0, drain, barrier
  STAGE(0);
  asm volatile("s_waitcnt vmcnt(0)" ::: "memory");
  SB0;
  __builtin_amdgcn_s_barrier();

  for (int t = 0; t < 128; ++t) {
    if (t < 127) STAGE(t + 1);

    const short8* ASb = ASBUF(t);
    const short8* BSb = BSBUF(t);
    short8 af[4], bv[4];
#pragma unroll
    for (int mi = 0; mi < 4; ++mi) af[mi] = ASb[a_b + mi * 64];
#pragma unroll
    for (int ni = 0; ni < 4; ++ni) bv[ni] = BSb[b_b + ni * 64];

    __builtin_amdgcn_s_setprio(1);
#pragma unroll
    for (int mi = 0; mi < 4; ++mi)
#pragma unroll
      for (int ni = 0; ni < 4; ++ni)
        acc[mi][ni] = __builtin_amdgcn_mfma_f32_16x16x32_bf16(af[mi], bv[ni],
                                                              acc[mi][ni], 0, 0, 0);
    __builtin_amdgcn_s_setprio(0);

    if (t < 127) {
      asm volatile("s_waitcnt vmcnt(0)" ::: "memory");
      SB0;
      __builtin_amdgcn_s_barrier();
      SB0;
    }
  }

  // epilogue: C/D layout col=lane&15, row=(lane>>4)*4+reg
  const int rr = (lane >> 4) * 4;
#pragma unroll
  for (int ni = 0; ni < 4; ++ni) {
    const int gn = n0 + wn * 64 + ni * 16 + fr;
    const float bvv = bias[gn];
#pragma unroll
    for (int mi = 0; mi < 4; ++mi) {
      const int gm = m0 + wm * 64 + mi * 16 + rr;
#pragma unroll
      for (int r = 0; r < 4; ++r)
        C[(size_t)(gm + r) * N_DIM + gn] = acc[mi][ni][r] + bvv;
    }
  }
}

extern "C" void kernel_launch(void* const* d_in, const int* in_sizes, int n_in,
                              void* d_out, int out_size, void* d_ws, size_t ws_size,
                              hipStream_t stream) {
  const float* x = (const float*)d_in[0];
  const int* wq = (const int*)d_in[1];
  const float* sc = (const float*)d_in[2];
  const float* zr = (const float*)d_in[3];
  const float* bias = (const float*)d_in[4];
  float* out = (float*)d_out;

  unsigned short* xb = (unsigned short*)d_ws;
  unsigned short* wt = (unsigned short*)((char*)d_ws + (size_t)M_DIM * K_DIM * 2);

  cvt_kernel<<<dim3(2048), dim3(256), 0, stream>>>(x, xb);
  dequant_kernel<<<dim3(1024), dim3(256), 0, stream>>>(wq, sc, zr, wt);
  gemm_bt_kernel<<<dim3(512), dim3(512), 0, stream>>>(xb, wt, bias, out);
}